// Round 3
// baseline (175.969 us; speedup 1.0000x reference)
//
#include <hip/hip_runtime.h>

typedef _Float16 half8 __attribute__((ext_vector_type(8)));
typedef float floatx4 __attribute__((ext_vector_type(4)));

#define IN_DIM 256
#define OUT_DIM 256

// Quantize weight -> f16 in MFMA-A-fragment-permuted order:
//   perm[((ct*8 + ks)*64 + lane)*8 + e] = rne(W[ct*16 + (lane&15)][ks*32 + (lane>>4)*8 + e] * 100)
// so each A-frag load in the gemm is one fully-coalesced 16B/lane dwordx4.
// Also quantizes bias and writes the tuple's scalar second output (s*scale).
__global__ void quant_kernel(const float* __restrict__ w,
                             const float* __restrict__ bias,
                             const float* __restrict__ in_scale,
                             _Float16* __restrict__ wqp,
                             float* __restrict__ bq,
                             float* __restrict__ out_scalar) {
    int t = blockIdx.x * blockDim.x + threadIdx.x;   // 8192 threads, 8 elems each
    if (t < (OUT_DIM * IN_DIM) / 8) {
        int lane = t & 63;
        int ks   = (t >> 6) & 7;
        int ct   = t >> 9;                           // 0..15
        int row  = ct * 16 + (lane & 15);
        int k0   = ks * 32 + (lane >> 4) * 8;
        const float* src = w + row * IN_DIM + k0;
        half8 h;
#pragma unroll
        for (int e = 0; e < 8; ++e)
            h[e] = (_Float16)rintf(src[e] * 100.0f); // jnp.round = round-half-even
        *((half8*)wqp + t) = h;
    }
    if (t < OUT_DIM) {
        float s2 = in_scale[0] * 100.0f;
        bq[t] = rintf(bias[t] * s2);
    }
    if (t == 0 && out_scalar != nullptr)
        out_scalar[0] = in_scale[0] * 100.0f;
}

// Barrier-free gemm: each wave owns a 16-row x 256-col output strip.
// B-frag (c_x) loaded directly from global (8 contiguous int32/lane, each
// 128B line fully consumed within one ks), A-frags (W) from the permuted
// L1/L2-hot buffer. No LDS, no __syncthreads -> pure streaming.
__global__ __launch_bounds__(256, 3) void gemm_kernel(const int* __restrict__ cx,
                                                      const _Float16* __restrict__ wqp,
                                                      const float* __restrict__ bq,
                                                      float* __restrict__ out) {
    const int t    = threadIdx.x;
    const int wave = t >> 6;
    const int lane = t & 63;
    const int m16  = lane & 15;
    const int quad = lane >> 4;

    const size_t row = (size_t)blockIdx.x * 64 + wave * 16 + m16;  // lane's batch row
    const int* crow = cx + row * IN_DIM;

    floatx4 acc[16] = {};                    // 16 col-tiles x 4 = 64 VGPRs
    const half8* wbase = (const half8*)wqp;  // units of 16B

#pragma unroll
    for (int ks = 0; ks < 8; ++ks) {
        // c_x B-fragment: k = ks*32 + quad*8 .. +8, contiguous per lane
        const int* cp = crow + ks * 32 + quad * 8;
        int4 c0 = *(const int4*)(cp);
        int4 c1 = *(const int4*)(cp + 4);
        half8 b;
        b[0] = (_Float16)(float)c0.x; b[1] = (_Float16)(float)c0.y;
        b[2] = (_Float16)(float)c0.z; b[3] = (_Float16)(float)c0.w;
        b[4] = (_Float16)(float)c1.x; b[5] = (_Float16)(float)c1.y;
        b[6] = (_Float16)(float)c1.z; b[7] = (_Float16)(float)c1.w;
#pragma unroll
        for (int ct = 0; ct < 16; ++ct) {
            half8 a = wbase[(ct * 8 + ks) * 64 + lane];   // coalesced, L1-hot
            acc[ct] = __builtin_amdgcn_mfma_f32_16x16x32_f16(a, b, acc[ct], 0, 0, 0);
        }
    }

    // Epilogue: D col(lane&15)=batch row (== our `row`), D row(quad*4+r)=out col
    // -> each lane stores 4 consecutive out cols as one float4, 16 tiles.
    float* orow = out + row * OUT_DIM;
#pragma unroll
    for (int ct = 0; ct < 16; ++ct) {
        int col = ct * 16 + quad * 4;
        floatx4 bv = *(const floatx4*)(bq + col);
        *(floatx4*)(orow + col) = acc[ct] + bv;
    }
}

extern "C" void kernel_launch(void* const* d_in, const int* in_sizes, int n_in,
                              void* d_out, int out_size, void* d_ws, size_t ws_size,
                              hipStream_t stream) {
    const int*   cx       = (const int*)d_in[0];
    const float* w        = (const float*)d_in[1];
    const float* bias     = (const float*)d_in[2];
    const float* in_scale = (const float*)d_in[3];
    float* out = (float*)d_out;

    _Float16* wqp = (_Float16*)d_ws;                              // 128 KB, permuted
    float*    bq  = (float*)((char*)d_ws + OUT_DIM * IN_DIM * 2); // 1 KB

    const int rows = in_sizes[0] / IN_DIM;          // 65536
    const size_t gemm_elems = (size_t)rows * OUT_DIM;
    float* out_scalar = ((size_t)out_size > gemm_elems) ? (out + gemm_elems) : nullptr;

    quant_kernel<<<32, 256, 0, stream>>>(w, bias, in_scale, wqp, bq, out_scalar);
    gemm_kernel<<<rows / 64, 256, 0, stream>>>(cx, wqp, bq, out);
}

// Round 4
// 128.455 us; speedup vs baseline: 1.3699x; 1.3699x over previous
//
#include <hip/hip_runtime.h>

typedef _Float16 half8 __attribute__((ext_vector_type(8)));
typedef _Float16 half4 __attribute__((ext_vector_type(4)));
typedef float floatx4 __attribute__((ext_vector_type(4)));

#define IN_DIM 256
#define OUT_DIM 256
#define ROWSTR 264  // 256 + 8 f16 pad: frag ds_read_b128 measured conflict-free (R2)

// Quantize weight -> f16 in MFMA-A-fragment-permuted order:
//   perm[((ct*8 + ks)*64 + lane)*8 + e] = rne(W[ct*16 + (lane&15)][ks*32 + (lane>>4)*8 + e] * 100)
// Each wave's A-frag loads are then coalesced dwordx4 from a 32KB (L1-resident) slice.
__global__ void quant_kernel(const float* __restrict__ w,
                             const float* __restrict__ bias,
                             const float* __restrict__ in_scale,
                             _Float16* __restrict__ wqp,
                             float* __restrict__ bq,
                             float* __restrict__ out_scalar) {
    int t = blockIdx.x * blockDim.x + threadIdx.x;
    if (t < (OUT_DIM * IN_DIM) / 8) {
        int lane = t & 63;
        int ks   = (t >> 6) & 7;
        int ct   = t >> 9;
        int row  = ct * 16 + (lane & 15);
        int k0   = ks * 32 + (lane >> 4) * 8;
        const float* src = w + row * IN_DIM + k0;
        half8 h;
#pragma unroll
        for (int e = 0; e < 8; ++e)
            h[e] = (_Float16)rintf(src[e] * 100.0f); // jnp.round = round-half-even
        *((half8*)wqp + t) = h;
    }
    if (t < OUT_DIM) {
        float s2 = in_scale[0] * 100.0f;
        bq[t] = rintf(bias[t] * s2);
    }
    if (t == 0 && out_scalar != nullptr)
        out_scalar[0] = in_scale[0] * 100.0f;
}

// ---- device helpers (forced inline) ----

__device__ __forceinline__ void stage_tile(const int* __restrict__ cbase, int t,
                                           _Float16* __restrict__ buf) {
#pragma unroll
    for (int i = 0; i < 16; ++i) {
        int flat = i * 1024 + t * 4;
        int4 v = *(const int4*)(cbase + flat);
        int row = flat >> 8;
        int col = flat & 255;
        half4 h;
        h.x = (_Float16)v.x; h.y = (_Float16)v.y;
        h.z = (_Float16)v.z; h.w = (_Float16)v.w;
        *(half4*)&buf[row * ROWSTR + col] = h;
    }
}

__device__ __forceinline__ void compute_tile(const _Float16* __restrict__ buf,
                                             const half8* __restrict__ wbase,
                                             int wave, int m16, int quad,
                                             floatx4 (&acc)[4][4]) {
#pragma unroll
    for (int ks = 0; ks < 8; ++ks) {
        half8 afr[4], bfr[4];
#pragma unroll
        for (int i = 0; i < 4; ++i)   // W from permuted global, wave's 32KB slice (L1-hot)
            afr[i] = wbase[((wave * 4 + i) * 8 + ks) * 64 + (quad * 16 + m16)];
        const int kb = ks * 32 + quad * 8;
#pragma unroll
        for (int j = 0; j < 4; ++j)   // c_x f16 from LDS, conflict-free
            bfr[j] = *(const half8*)&buf[(j * 16 + m16) * ROWSTR + kb];
#pragma unroll
        for (int i = 0; i < 4; ++i)
#pragma unroll
            for (int j = 0; j < 4; ++j)
                acc[i][j] = __builtin_amdgcn_mfma_f32_16x16x32_f16(afr[i], bfr[j], acc[i][j], 0, 0, 0);
    }
}

__device__ __forceinline__ void store_tile(float* __restrict__ out, size_t m0,
                                           const float* __restrict__ bq,
                                           int wave, int m16, int quad,
                                           floatx4 (&acc)[4][4]) {
#pragma unroll
    for (int i = 0; i < 4; ++i) {
        int col = wave * 64 + i * 16 + quad * 4;
        floatx4 bv = *(const floatx4*)(bq + col);
#pragma unroll
        for (int j = 0; j < 4; ++j) {
            size_t row = m0 + j * 16 + m16;
            *(floatx4*)(out + row * OUT_DIM + col) = acc[i][j] + bv;
        }
    }
}

// 2 tiles (64 rows each) per block, double-buffered LDS. Pipeline:
// stage T0 | barrier | issue T1 loads -> compute T0 (loads in flight) |
// cvt+ds_write T1 | store T0 | barrier | compute T1 | store T1.
__global__ __launch_bounds__(256, 2) void gemm_kernel(const int* __restrict__ cx,
                                                      const _Float16* __restrict__ wqp,
                                                      const float* __restrict__ bq,
                                                      float* __restrict__ out) {
    __shared__ _Float16 buf0[64 * ROWSTR];
    __shared__ _Float16 buf1[64 * ROWSTR];

    const int t    = threadIdx.x;
    const int wave = t >> 6;
    const int lane = t & 63;
    const int m16  = lane & 15;
    const int quad = lane >> 4;

    const size_t m0   = (size_t)blockIdx.x * 128;   // tile pair base row
    const int* cbase0 = cx + m0 * IN_DIM;
    const int* cbase1 = cbase0 + 64 * IN_DIM;
    const half8* wbase = (const half8*)wqp;

    // ---- stage T0 ----
    stage_tile(cbase0, t, buf0);
    __syncthreads();

    // ---- issue T1 global loads (kept in VGPRs, in flight under compute T0) ----
    int4 creg[16];
#pragma unroll
    for (int i = 0; i < 16; ++i)
        creg[i] = *(const int4*)(cbase1 + i * 1024 + t * 4);

    // ---- compute T0 ----
    floatx4 acc0[4][4] = {};
    compute_tile(buf0, wbase, wave, m16, quad, acc0);

    // ---- cvt + ds_write T1 into buf1 ----
#pragma unroll
    for (int i = 0; i < 16; ++i) {
        int flat = i * 1024 + t * 4;
        int row = flat >> 8;
        int col = flat & 255;
        half4 h;
        h.x = (_Float16)creg[i].x; h.y = (_Float16)creg[i].y;
        h.z = (_Float16)creg[i].z; h.w = (_Float16)creg[i].w;
        *(half4*)&buf1[row * ROWSTR + col] = h;
    }

    // ---- store T0 (frees acc0 before T1 compute) ----
    store_tile(out, m0, bq, wave, m16, quad, acc0);

    __syncthreads();

    // ---- compute + store T1 ----
    floatx4 acc1[4][4] = {};
    compute_tile(buf1, wbase, wave, m16, quad, acc1);
    store_tile(out, m0 + 64, bq, wave, m16, quad, acc1);
}

extern "C" void kernel_launch(void* const* d_in, const int* in_sizes, int n_in,
                              void* d_out, int out_size, void* d_ws, size_t ws_size,
                              hipStream_t stream) {
    const int*   cx       = (const int*)d_in[0];
    const float* w        = (const float*)d_in[1];
    const float* bias     = (const float*)d_in[2];
    const float* in_scale = (const float*)d_in[3];
    float* out = (float*)d_out;

    _Float16* wqp = (_Float16*)d_ws;                              // 128 KB, permuted
    float*    bq  = (float*)((char*)d_ws + OUT_DIM * IN_DIM * 2); // 1 KB

    const int rows = in_sizes[0] / IN_DIM;          // 65536
    const size_t gemm_elems = (size_t)rows * OUT_DIM;
    float* out_scalar = ((size_t)out_size > gemm_elems) ? (out + gemm_elems) : nullptr;

    quant_kernel<<<32, 256, 0, stream>>>(w, bias, in_scale, wqp, bq, out_scalar);
    gemm_kernel<<<rows / 128, 256, 0, stream>>>(cx, wqp, bq, out);
}